// Round 12
// baseline (269.972 us; speedup 1.0000x reference)
//
#include <hip/hip_runtime.h>
#include <math.h>

// Problem constants (reference: S=256, B=2, HID=512, NH=8, HD=64, C=1)
constexpr int S_   = 256;
constexpr int B_   = 2;
constexpr int HID_ = 512;
constexpr int NH_  = 8;
constexpr int HD_  = 64;
constexpr int BSH  = B_ * S_ * HID_;   // 262144

// R12: R11's cooperative launch never executed (probs==0 => silent launch
// failure under graph capture / co-residency check). Same gap-elimination
// goal via "last-block-does-epilogue" atomics instead (no co-residency or
// dispatch-order assumptions): gemm+mobius fused (cnt[rt], 8 tiles/rowgroup),
// attn+outproj fused (cntA[b*32+qt], 8 heads/(b,qtile)). 4 launches -> 2.
// All stage bodies verbatim from R10 best (105.6us, absmax 3.05e-5).

typedef unsigned short u16;
typedef short s16x8 __attribute__((ext_vector_type(8)));
typedef float f32x4 __attribute__((ext_vector_type(4)));

__device__ __forceinline__ float artanh_c(float x) {
    x = fminf(fmaxf(x, -0.9999999f), 0.9999999f);
    return 0.5f * __logf((1.f + x) / (1.f - x));
}

__device__ __forceinline__ float wsum64(float v) {
    #pragma unroll
    for (int o = 1; o < 64; o <<= 1) v += __shfl_xor(v, o, 64);
    return v;
}

__device__ __forceinline__ void split8(const float* v, s16x8& hi, s16x8& lo) {
    #pragma unroll
    for (int j = 0; j < 8; ++j) {
        const unsigned u = __float_as_uint(v[j]);
        const float hf = __uint_as_float(u & 0xFFFF0000u);
        hi[j] = (short)(u >> 16);
        lo[j] = (short)(__float_as_uint(v[j] - hf) >> 16);
    }
}

// ---------------------------------------------------------------------------
// Stage 1a+1b fused: bf16-MFMA gemm (R4 structure, 5.2us) + last-block mobius
// epilogue. 8 blocks per 32-row group; the 8th arriver (acq_rel agent-scope
// atomic) runs the mobius rows inline (barrier-free body: shuffles only).
// ---------------------------------------------------------------------------
__global__ __launch_bounds__(256) void gemm3_mobius_kernel(
    const float* __restrict__ query,
    const float* __restrict__ Wq, const float* __restrict__ bq,
    const float* __restrict__ Wk, const float* __restrict__ bk,
    const float* __restrict__ Wv, const float* __restrict__ bv,
    float* __restrict__ ws_qkv, float* __restrict__ ws_gamma,
    unsigned int* __restrict__ cnt)
{
    const int tid = threadIdx.x;
    const int rt = blockIdx.x >> 3;            // 0..47 (32-row tiles over 1536)
    const int ct = blockIdx.x & 7;             // 0..7  (64-col tiles)
    const int which = (rt * 32) >> 9;
    const int rloc  = (rt * 32) & 511;
    const float* __restrict__ W = (which == 0) ? Wq : (which == 1) ? Wk : Wv;

    __shared__ __align__(16) u16 sA[2][2][32 * 64];   // 16 KB
    __shared__ __align__(16) u16 sB[2][2][64 * 64];   // 32 KB
    __shared__ unsigned int lastS;

    const int ra = tid >> 3, sa = tid & 7;
    const int rb = tid >> 2, hb = (tid & 3) * 2;
    const int axrow = rloc + ra;
    const float* gA = query + (size_t)((axrow & 255) * 2 + (axrow >> 8)) * HID_ + sa * 8;
    const float* gB = W + (size_t)(ct * 64 + rb) * HID_ + hb * 8;
    const int wA  = ra * 64 + ((sa ^ (ra & 7)) * 8);
    const int wB0 = rb * 64 + ((hb ^ (rb & 7)) * 8);
    const int wB1 = rb * 64 + (((hb + 1) ^ (rb & 7)) * 8);

    const int lane = tid & 63, wvg = tid >> 6;
    const int fr = lane & 15, fs = lane >> 4;
    const int aB0 = fr * 64,        ax0 = fr & 7;
    const int aB1 = (16 + fr) * 64, ax1 = (16 + fr) & 7;
    const int bB  = (wvg * 16 + fr) * 64, bx = (wvg * 16 + fr) & 7;

    float a8[8], b16[16];
    f32x4 acc[2] = {(f32x4){0.f,0.f,0.f,0.f}, (f32x4){0.f,0.f,0.f,0.f}};

#define G3_LOAD(c)  do { \
        const int k0 = (c) * 64; \
        *(float4*)&a8[0]  = *(const float4*)(gA + k0); \
        *(float4*)&a8[4]  = *(const float4*)(gA + k0 + 4); \
        *(float4*)&b16[0] = *(const float4*)(gB + k0); \
        *(float4*)&b16[4] = *(const float4*)(gB + k0 + 4); \
        *(float4*)&b16[8] = *(const float4*)(gB + k0 + 8); \
        *(float4*)&b16[12]= *(const float4*)(gB + k0 + 12); \
    } while (0)

#define G3_WRITE(b) do { \
        s16x8 h_, l_; \
        split8(a8, h_, l_); \
        *(s16x8*)&sA[b][0][wA] = h_;  *(s16x8*)&sA[b][1][wA] = l_; \
        split8(&b16[0], h_, l_); \
        *(s16x8*)&sB[b][0][wB0] = h_; *(s16x8*)&sB[b][1][wB0] = l_; \
        split8(&b16[8], h_, l_); \
        *(s16x8*)&sB[b][0][wB1] = h_; *(s16x8*)&sB[b][1][wB1] = l_; \
    } while (0)

    G3_LOAD(0);
    G3_WRITE(0);

    for (int c = 0; c < 8; ++c) {
        const int p = c & 1;
        __syncthreads();
        if (c < 7) G3_LOAD(c + 1);
        #pragma unroll
        for (int h = 0; h < 2; ++h) {
            const int sl = h * 4 + fs;
            s16x8 ah0 = *(const s16x8*)&sA[p][0][aB0 + ((sl ^ ax0) * 8)];
            s16x8 al0 = *(const s16x8*)&sA[p][1][aB0 + ((sl ^ ax0) * 8)];
            s16x8 ah1 = *(const s16x8*)&sA[p][0][aB1 + ((sl ^ ax1) * 8)];
            s16x8 al1 = *(const s16x8*)&sA[p][1][aB1 + ((sl ^ ax1) * 8)];
            s16x8 bh  = *(const s16x8*)&sB[p][0][bB  + ((sl ^ bx)  * 8)];
            s16x8 bl  = *(const s16x8*)&sB[p][1][bB  + ((sl ^ bx)  * 8)];
            acc[0] = __builtin_amdgcn_mfma_f32_16x16x32_bf16(ah0, bh, acc[0], 0, 0, 0);
            acc[0] = __builtin_amdgcn_mfma_f32_16x16x32_bf16(ah0, bl, acc[0], 0, 0, 0);
            acc[0] = __builtin_amdgcn_mfma_f32_16x16x32_bf16(al0, bh, acc[0], 0, 0, 0);
            acc[1] = __builtin_amdgcn_mfma_f32_16x16x32_bf16(ah1, bh, acc[1], 0, 0, 0);
            acc[1] = __builtin_amdgcn_mfma_f32_16x16x32_bf16(ah1, bl, acc[1], 0, 0, 0);
            acc[1] = __builtin_amdgcn_mfma_f32_16x16x32_bf16(al1, bh, acc[1], 0, 0, 0);
        }
        if (c < 7) G3_WRITE((c + 1) & 1);
    }
#undef G3_LOAD
#undef G3_WRITE

    #pragma unroll
    for (int i = 0; i < 2; ++i)
        #pragma unroll
        for (int q = 0; q < 4; ++q)
            ws_qkv[(size_t)(rt * 32 + i * 16 + fs * 4 + q) * HID_ + ct * 64 + wvg * 16 + fr]
                = acc[i][q];

    // ---- last-block mobius epilogue for rows rt*32 .. rt*32+31 ----
    __threadfence();
    if (tid == 0) {
        const unsigned int old = __hip_atomic_fetch_add(&cnt[rt], 1u,
                                    __ATOMIC_ACQ_REL, __HIP_MEMORY_SCOPE_AGENT);
        lastS = (old == 7u) ? 1u : 0u;
    }
    __syncthreads();
    if (lastS == 0u) return;
    __threadfence();   // acquire: see the other 7 blocks' ws_mx tiles

    #pragma unroll 1
    for (int i = 0; i < 8; ++i) {
        const int row  = rt * 32 + wvg * 8 + i;   // wave wvg: 8 rows
        const int wch  = row >> 9;
        const int rr   = row & 511;
        const float* __restrict__ bias = (wch == 0) ? bq : (wch == 1) ? bk : bv;
        float* mrow = ws_qkv + (size_t)row * HID_;
        const float* xrow = query + (size_t)((rr & 255) * 2 + (rr >> 8)) * HID_;

        float m[8], x[8], bb[8];
        *(float4*)&m[0]  = ((const float4*)mrow)[lane * 2];
        *(float4*)&m[4]  = ((const float4*)mrow)[lane * 2 + 1];
        *(float4*)&x[0]  = ((const float4*)xrow)[lane * 2];
        *(float4*)&x[4]  = ((const float4*)xrow)[lane * 2 + 1];
        *(float4*)&bb[0] = ((const float4*)bias)[lane * 2];
        *(float4*)&bb[4] = ((const float4*)bias)[lane * 2 + 1];

        float x2p = 0.f, m2p = 0.f, b2p = 0.f;
        #pragma unroll
        for (int j = 0; j < 8; ++j) {
            x2p = fmaf(x[j], x[j], x2p);
            m2p = fmaf(m[j], m[j], m2p);
            b2p = fmaf(bb[j], bb[j], b2p);
        }
        const float x2s = wsum64(x2p);
        const float mn2 = wsum64(m2p);
        const float b2s = wsum64(b2p);
        const float xn = fmaxf(sqrtf(x2s), 1e-15f);
        const float mn = fmaxf(sqrtf(mn2), 1e-15f);
        const float fac = tanhf(mn / xn * artanh_c(xn)) / mn;
        float r[8];
        float r2p = 0.f, ryp = 0.f;
        #pragma unroll
        for (int j = 0; j < 8; ++j) {
            r[j] = fac * m[j];
            r2p = fmaf(r[j], r[j], r2p);
            ryp = fmaf(r[j], bb[j], ryp);
        }
        const float r2s = wsum64(r2p);
        const float ry  = wsum64(ryp);
        const float a_c = 1.f + 2.f * ry + b2s;
        const float b_c = 1.f - r2s;
        const float den = 1.f + 2.f * ry + r2s * b2s;
        const float inv_den = 1.f / fmaxf(den, 1e-15f);
        float h[8];
        float h2p = 0.f;
        #pragma unroll
        for (int j = 0; j < 8; ++j) {
            h[j] = (a_c * r[j] + b_c * bb[j]) * inv_den;
            h2p = fmaf(h[j], h[j], h2p);
        }
        const float h2s = wsum64(h2p);
        float hn = fmaxf(sqrtf(h2s), 1e-15f);
        float pf = 1.f;
        if (hn > 0.996f) { pf = 0.996f / hn; hn = 0.996f; }
        const float lf = artanh_c(hn) / hn * pf;
        float l[8];
        float l2p = 0.f;
        #pragma unroll
        for (int j = 0; j < 8; ++j) {
            l[j] = lf * h[j];
            l2p = fmaf(l[j], l[j], l2p);
        }
        float cs = l2p;
        cs += __shfl_xor(cs, 1, 64);
        cs += __shfl_xor(cs, 2, 64);
        cs += __shfl_xor(cs, 4, 64);
        const float cn = fmaxf(sqrtf(cs), 1e-15f);
        const float th = tanhf(cn);
        const float sc = th / cn;
        float o[8];
        #pragma unroll
        for (int j = 0; j < 8; ++j) o[j] = sc * l[j];
        ((float4*)mrow)[lane * 2]     = *(float4*)&o[0];
        ((float4*)mrow)[lane * 2 + 1] = *(float4*)&o[4];
        if (wch == 2 && (lane & 7) == 0) {
            const int j = lane >> 3;
            ws_gamma[(size_t)rr * NH_ + j] = 2.f / fmaxf(1.f - th * th, 1e-15f);
        }
    }
}

// ---------------------------------------------------------------------------
// Stage 2+3+4 fused: attn v5 (R10: v2 skeleton 512x512 + grouped rcp) +
// last-block outproj epilogue. 8 head-blocks share each (b, q-tile) group;
// the 8th arriver computes outproj for its 8 s rows (per-wave reduce).
// ---------------------------------------------------------------------------
__global__ __launch_bounds__(512, 4) void attn_outproj_kernel(
    const float* __restrict__ ws_qkv, const float* __restrict__ gamma,
    float* __restrict__ probs, float* __restrict__ lc,
    float* __restrict__ out0, unsigned int* __restrict__ cntA)
{
    const int tid = threadIdx.x;
    const int bh  = blockIdx.x >> 5;
    const int q0  = (blockIdx.x & 31) * 8;
    const float* __restrict__ ql = ws_qkv + (size_t)bh * (S_ * HD_);
    const float* __restrict__ kl = ws_qkv + (size_t)BSH + (size_t)bh * (S_ * HD_);
    const float* __restrict__ vl = ws_qkv + (size_t)2 * BSH + (size_t)bh * (S_ * HD_);

    __shared__ __align__(16) float kS[128 * 64];   // 32 KB
    __shared__ __align__(16) float qS[8 * 64];
    __shared__ __align__(16) float pS[8 * 256];
    __shared__ float gS[S_];
    __shared__ float k2S[128];
    __shared__ float nomP[8][8][64];               // 16 KB
    __shared__ float dnS[8];
    __shared__ unsigned int lastS;

    if (tid < 256) gS[tid] = gamma[(size_t)bh * S_ + tid];
    if (tid < 128) ((float4*)qS)[tid] = ((const float4*)(ql + (size_t)q0 * 64))[tid];
    __syncthreads();

    const int lane = tid & 63;
    const int q_l  = tid >> 6;        // wave id == q index
    const int n_i  = lane & 31;
    const int dh   = lane >> 5;
    const int d0   = dh * 32;

    float qv[32];
    #pragma unroll
    for (int c = 0; c < 8; ++c)
        *(float4*)&qv[c * 4] = *(const float4*)&qS[q_l * 64 + d0 + c * 4];
    float q2p = 0.f;
    #pragma unroll
    for (int d = 0; d < 32; ++d) q2p = fmaf(qv[d], qv[d], q2p);
    const float q2 = q2p + __shfl_xor(q2p, 32, 64);
    const float b_c = 1.f - q2;
    float* __restrict__ prow = probs + ((size_t)(bh * S_ + q0 + q_l)) * S_;

    const int c4 = tid & 15;
    const int nb = tid >> 4;
    float sp = 0.f, spg = 0.f;

    for (int half = 0; half < 2; ++half) {
        __syncthreads();
        #pragma unroll
        for (int jj = 0; jj < 4; ++jj) {
            const int n = nb + 32 * jj;
            const float4 v = *(const float4*)(kl + ((size_t)(half * 128 + n)) * 64 + c4 * 4);
            *(float4*)&kS[n * 64 + ((c4 ^ (n & 15)) * 4)] = v;
            float pk = fmaf(v.x, v.x, fmaf(v.y, v.y, fmaf(v.z, v.z, v.w * v.w)));
            pk += __shfl_xor(pk, 1, 64);
            pk += __shfl_xor(pk, 2, 64);
            pk += __shfl_xor(pk, 4, 64);
            pk += __shfl_xor(pk, 8, 64);
            if (c4 == 0) k2S[n] = pk;
        }
        __syncthreads();
        #pragma unroll
        for (int j = 0; j < 4; ++j) {
            const int n = n_i + 32 * j;
            float kv[32];
            #pragma unroll
            for (int c = 0; c < 8; ++c) {
                const int sl = dh * 8 + c;
                *(float4*)&kv[c * 4] = *(const float4*)&kS[n * 64 + ((sl ^ (n & 15)) * 4)];
            }
            float s0 = 0.f, s1 = 0.f;
            #pragma unroll
            for (int d = 0; d < 32; d += 2) {
                s0 = fmaf(qv[d],     kv[d],     s0);
                s1 = fmaf(qv[d + 1], kv[d + 1], s1);
            }
            float s = s0 + s1;
            s += __shfl_xor(s, 32, 64);
            const float k2  = k2S[n];
            const float a_c = 1.f - 2.f * s + k2;
            const float den = fmaxf(fmaf(q2, k2, 1.f - 2.f * s), 1e-15f);
            const float ra  = __builtin_amdgcn_rcpf(a_c);
            const float r_c = b_c * ra;
            const float scale = den * den * ra * ra;
            const float c2  = 1e-30f * scale;
            float isA = 0.f, isB = 0.f;
            #pragma unroll
            for (int g = 0; g < 8; g += 2) {
                {
                    const int bse = g * 4;
                    const float w0 = fmaf(r_c, kv[bse + 0], -qv[bse + 0]);
                    const float w1 = fmaf(r_c, kv[bse + 1], -qv[bse + 1]);
                    const float w2 = fmaf(r_c, kv[bse + 2], -qv[bse + 2]);
                    const float w3 = fmaf(r_c, kv[bse + 3], -qv[bse + 3]);
                    const float ga = fmaf(w0, w0, c2), gb = fmaf(w1, w1, c2);
                    const float gc = fmaf(w2, w2, c2), gd = fmaf(w3, w3, c2);
                    const float pab = ga * gb, pcd = gc * gd;
                    const float num = fmaf(ga + gb, pcd, (gc + gd) * pab);
                    isA = fmaf(num, __builtin_amdgcn_rcpf(pab * pcd), isA);
                }
                {
                    const int bse = (g + 1) * 4;
                    const float w0 = fmaf(r_c, kv[bse + 0], -qv[bse + 0]);
                    const float w1 = fmaf(r_c, kv[bse + 1], -qv[bse + 1]);
                    const float w2 = fmaf(r_c, kv[bse + 2], -qv[bse + 2]);
                    const float w3 = fmaf(r_c, kv[bse + 3], -qv[bse + 3]);
                    const float ga = fmaf(w0, w0, c2), gb = fmaf(w1, w1, c2);
                    const float gc = fmaf(w2, w2, c2), gd = fmaf(w3, w3, c2);
                    const float pab = ga * gb, pcd = gc * gd;
                    const float num = fmaf(ga + gb, pcd, (gc + gd) * pab);
                    isB = fmaf(num, __builtin_amdgcn_rcpf(pab * pcd), isB);
                }
            }
            float invsum = isA + isB;
            invsum += __shfl_xor(invsum, 32, 64);
            const float t1 = __builtin_amdgcn_rsqf(scale * invsum);
            const float p = 0.5f - 0.5f * fminf(t1, 0.9999999f);
            const int gn = half * 128 + n;
            if (dh == 0) {
                prow[gn] = p;
                const float g = gS[gn];
                pS[q_l * 256 + gn] = p * g;
                sp += p; spg += p * g;
            }
        }
    }
    sp  = wsum64(sp);
    spg = wsum64(spg);
    if (lane == 0) dnS[q_l] = spg - sp;
    __syncthreads();

    // Phase B: wave w owns n in [32w, 32w+32), all 8 q; lane = d
    const int w = q_l, d = lane;
    float acc[8] = {};
    const float* __restrict__ vbase = vl + (size_t)(w * 32) * 64;
    #pragma unroll
    for (int i4 = 0; i4 < 8; ++i4) {
        float vv[4];
        #pragma unroll
        for (int j2 = 0; j2 < 4; ++j2) vv[j2] = vbase[(size_t)(i4 * 4 + j2) * 64 + d];
        #pragma unroll
        for (int qq = 0; qq < 8; ++qq) {
            const float4 pq = *(const float4*)&pS[qq * 256 + w * 32 + i4 * 4];
            acc[qq] = fmaf(pq.x, vv[0], acc[qq]);
            acc[qq] = fmaf(pq.y, vv[1], acc[qq]);
            acc[qq] = fmaf(pq.z, vv[2], acc[qq]);
            acc[qq] = fmaf(pq.w, vv[3], acc[qq]);
        }
    }
    #pragma unroll
    for (int qq = 0; qq < 8; ++qq) nomP[w][qq][d] = acc[qq];
    __syncthreads();

    {
        const int qq = q_l;
        float nom = 0.f;
        #pragma unroll
        for (int w2 = 0; w2 < 8; ++w2) nom += nomP[w2][qq][d];
        const float dd = dnS[qq];
        const float adn = fmaxf(fabsf(dd), 1e-10f);
        const float sden = (dd >= 0.f) ? adn : -adn;
        const float m = nom / sden;
        const float ss = wsum64(m * m);
        const float nn = fmaxf(sqrtf(ss), 1e-15f);
        const float s1 = tanhf(0.5f * artanh_c(nn));
        const float res = s1 * m / nn;
        const float nres = fmaxf(s1, 1e-15f);
        lc[((size_t)(bh * S_ + q0 + qq)) * HD_ + d] = (artanh_c(nres) / nres) * res;
    }

    // ---- last-block outproj epilogue for s = q0..q0+7 of this b ----
    __threadfence();
    const int b = bh >> 3;
    if (tid == 0) {
        const unsigned int old = __hip_atomic_fetch_add(&cntA[b * 32 + (q0 >> 3)], 1u,
                                    __ATOMIC_ACQ_REL, __HIP_MEMORY_SCOPE_AGENT);
        lastS = (old == 7u) ? 1u : 0u;
    }
    __syncthreads();
    if (lastS == 0u) return;
    __threadfence();   // acquire: see all 8 heads' lc rows

    {
        // wave g handles s = q0+g; lane l handles elems e = l*8..l*8+7
        // (h = l>>3 constant per lane, d = (l&7)*8 + j)
        const int g = tid >> 6, l = tid & 63;
        const int s = q0 + g;
        const int h = l >> 3, dv = (l & 7) * 8;
        const float* src = lc + (((size_t)(b * NH_ + h)) * S_ + s) * HD_ + dv;
        float v[8];
        *(float4*)&v[0] = *(const float4*)src;
        *(float4*)&v[4] = *(const float4*)(src + 4);
        float pp = 0.f;
        #pragma unroll
        for (int j = 0; j < 8; ++j) pp = fmaf(v[j], v[j], pp);
        const float ss = wsum64(pp);                  // 512-elem row sum
        const float nn = fmaxf(sqrtf(ss), 1e-15f);
        const float f = tanhf(nn) / nn;
        float* orow = out0 + ((size_t)(s * B_ + b)) * HID_ + l * 8;
        float o[8];
        #pragma unroll
        for (int j = 0; j < 8; ++j) o[j] = f * v[j];
        *(float4*)&orow[0] = *(float4*)&o[0];
        *(float4*)&orow[4] = *(float4*)&o[4];
    }
}

extern "C" void kernel_launch(void* const* d_in, const int* in_sizes, int n_in,
                              void* d_out, int out_size, void* d_ws, size_t ws_size,
                              hipStream_t stream) {
    (void)in_sizes; (void)n_in; (void)out_size; (void)ws_size;
    const float* query = (const float*)d_in[0];
    const float* Wq = (const float*)d_in[1];
    const float* bq = (const float*)d_in[2];
    const float* Wk = (const float*)d_in[3];
    const float* bk = (const float*)d_in[4];
    const float* Wv = (const float*)d_in[5];
    const float* bv = (const float*)d_in[6];

    float* out0  = (float*)d_out;                          // [S,B,HID] = 262144
    float* probs = out0 + (size_t)S_ * B_ * HID_;          // [B,NH,S,S] = 1048576

    float* ws       = (float*)d_ws;
    float* ws_qkv   = ws;                                  // 3*262144 floats
    float* ws_gamma = ws + (size_t)3 * BSH;                // 4096 floats
    float* ws_lc    = ws + (size_t)3 * BSH + 4096;         // 131072 floats
    unsigned int* cnt  = (unsigned int*)(ws_lc + 131072);  // 48 gemm + 64 attn
    unsigned int* cntA = cnt + 48;

    hipMemsetAsync(cnt, 0, 112 * sizeof(unsigned int), stream);
    gemm3_mobius_kernel<<<dim3(384), dim3(256), 0, stream>>>(
        query, Wq, bq, Wk, bk, Wv, bv, ws_qkv, ws_gamma, cnt);
    attn_outproj_kernel<<<dim3(512), dim3(512), 0, stream>>>(
        ws_qkv, ws_gamma, probs, ws_lc, out0, cntA);
}

// Round 13
// 104.800 us; speedup vs baseline: 2.5761x; 2.5761x over previous
//
#include <hip/hip_runtime.h>
#include <math.h>

// Problem constants (reference: S=256, B=2, HID=512, NH=8, HD=64, C=1)
constexpr int S_   = 256;
constexpr int B_   = 2;
constexpr int HID_ = 512;
constexpr int NH_  = 8;
constexpr int HD_  = 64;
constexpr int BSH  = B_ * S_ * HID_;   // 262144

// FINAL (R13 = R10 verbatim, session best 105.6us, absmax 3.05e-5).
// Session ledger: 129.3 (start) -> 105.6 (-18%).
//  - gemm3: bf16-MFMA hi/lo split (C = Ahi*Bhi + Ahi*Blo + Alo*Bhi), fused
//    cvt-in-staging, ping-pong LDS, 1 barrier/K-chunk. Measured 5.2us (R5).
//  - attn: 512blk x 512thr q-tile-8 skeleton (best single-shot family) +
//    d-split lane pairs + 4-term grouped rcp (8 rcp/lane vs 32; R8-validated).
//  - Dead ends (measured): cooperative launch no-ops under graph capture
//    (R11); atomic last-block cross-XCD fusion slow + coherence-marginal
//    (R12: 270us, absmax 9.5e-3). Launch gaps (~15us) unreachable in-harness.
//  - Warm rep-probe times understate cold single-shot by >10us (R8 vs R9):
//    probes rank inner loops, single-shot ranks skeletons.

typedef unsigned short u16;
typedef short s16x8 __attribute__((ext_vector_type(8)));
typedef float f32x4 __attribute__((ext_vector_type(4)));

__device__ __forceinline__ float artanh_c(float x) {
    // reference _artanh: clip to [-1+1e-7, 1-1e-7], then artanh
    x = fminf(fmaxf(x, -0.9999999f), 0.9999999f);
    return 0.5f * __logf((1.f + x) / (1.f - x));
}

__device__ __forceinline__ float wsum64(float v) {
    #pragma unroll
    for (int o = 1; o < 64; o <<= 1) v += __shfl_xor(v, o, 64);
    return v;
}

__device__ __forceinline__ float block_sum_256(float v, float* red) {
    const int t = threadIdx.x;
    __syncthreads();              // protect previous use of red
    red[t] = v;
    __syncthreads();
    #pragma unroll
    for (int sft = 128; sft > 0; sft >>= 1) {
        if (t < sft) red[t] += red[t + sft];
        __syncthreads();
    }
    return red[0];
}

// fp32 -> bf16 hi/lo split (exact residual: a = hi + lo + O(2^-16 a))
__device__ __forceinline__ void split8(const float* v, s16x8& hi, s16x8& lo) {
    #pragma unroll
    for (int j = 0; j < 8; ++j) {
        const unsigned u = __float_as_uint(v[j]);
        const float hf = __uint_as_float(u & 0xFFFF0000u);
        hi[j] = (short)(u >> 16);
        lo[j] = (short)(__float_as_uint(v[j] - hf) >> 16);
    }
}

// ---------------------------------------------------------------------------
// Stage 1a: mx = x @ W^T via bf16 MFMA, hi/lo compensated (R4 structure,
// measured 5.2us in the R5 probe).
// ---------------------------------------------------------------------------
__global__ __launch_bounds__(256) void gemm3_fused_kernel(
    const float* __restrict__ query,
    const float* __restrict__ Wq, const float* __restrict__ Wk,
    const float* __restrict__ Wv, float* __restrict__ ws_mx)
{
    const int tid = threadIdx.x;
    const int rt = blockIdx.x >> 3;            // 0..47 (32-row tiles over 1536)
    const int ct = blockIdx.x & 7;             // 0..7  (64-col tiles)
    const int which = (rt * 32) >> 9;
    const int rloc  = (rt * 32) & 511;
    const float* __restrict__ W = (which == 0) ? Wq : (which == 1) ? Wk : Wv;

    __shared__ __align__(16) u16 sA[2][2][32 * 64];   // [buf][hi/lo] 16 KB
    __shared__ __align__(16) u16 sB[2][2][64 * 64];   // [buf][hi/lo] 32 KB

    // staging: A thread -> (row ra, slice sa); B thread -> (row rb, slices hb,hb+1)
    const int ra = tid >> 3, sa = tid & 7;
    const int rb = tid >> 2, hb = (tid & 3) * 2;
    const int axrow = rloc + ra;
    const float* gA = query + (size_t)((axrow & 255) * 2 + (axrow >> 8)) * HID_ + sa * 8;
    const float* gB = W + (size_t)(ct * 64 + rb) * HID_ + hb * 8;
    const int wA  = ra * 64 + ((sa ^ (ra & 7)) * 8);
    const int wB0 = rb * 64 + ((hb ^ (rb & 7)) * 8);
    const int wB1 = rb * 64 + (((hb + 1) ^ (rb & 7)) * 8);

    // compute: wave wv owns cols wv*16+[0,16), all 32 rows (2 A-frags)
    const int lane = tid & 63, wv = tid >> 6;
    const int fr = lane & 15, fs = lane >> 4;
    const int aB0 = fr * 64,        ax0 = fr & 7;
    const int aB1 = (16 + fr) * 64, ax1 = (16 + fr) & 7;
    const int bB  = (wv * 16 + fr) * 64, bx = (wv * 16 + fr) & 7;

    float a8[8], b16[16];
    f32x4 acc[2] = {(f32x4){0.f,0.f,0.f,0.f}, (f32x4){0.f,0.f,0.f,0.f}};

#define G3_LOAD(c)  do { \
        const int k0 = (c) * 64; \
        *(float4*)&a8[0]  = *(const float4*)(gA + k0); \
        *(float4*)&a8[4]  = *(const float4*)(gA + k0 + 4); \
        *(float4*)&b16[0] = *(const float4*)(gB + k0); \
        *(float4*)&b16[4] = *(const float4*)(gB + k0 + 4); \
        *(float4*)&b16[8] = *(const float4*)(gB + k0 + 8); \
        *(float4*)&b16[12]= *(const float4*)(gB + k0 + 12); \
    } while (0)

#define G3_WRITE(b) do { \
        s16x8 h_, l_; \
        split8(a8, h_, l_); \
        *(s16x8*)&sA[b][0][wA] = h_;  *(s16x8*)&sA[b][1][wA] = l_; \
        split8(&b16[0], h_, l_); \
        *(s16x8*)&sB[b][0][wB0] = h_; *(s16x8*)&sB[b][1][wB0] = l_; \
        split8(&b16[8], h_, l_); \
        *(s16x8*)&sB[b][0][wB1] = h_; *(s16x8*)&sB[b][1][wB1] = l_; \
    } while (0)

    G3_LOAD(0);
    G3_WRITE(0);

    for (int c = 0; c < 8; ++c) {
        const int p = c & 1;
        __syncthreads();                     // buf p written & prior reads done
        if (c < 7) G3_LOAD(c + 1);           // issued after barrier: latency
                                             // covered by compute below
        #pragma unroll
        for (int h = 0; h < 2; ++h) {
            const int sl = h * 4 + fs;
            s16x8 ah0 = *(const s16x8*)&sA[p][0][aB0 + ((sl ^ ax0) * 8)];
            s16x8 al0 = *(const s16x8*)&sA[p][1][aB0 + ((sl ^ ax0) * 8)];
            s16x8 ah1 = *(const s16x8*)&sA[p][0][aB1 + ((sl ^ ax1) * 8)];
            s16x8 al1 = *(const s16x8*)&sA[p][1][aB1 + ((sl ^ ax1) * 8)];
            s16x8 bh  = *(const s16x8*)&sB[p][0][bB  + ((sl ^ bx)  * 8)];
            s16x8 bl  = *(const s16x8*)&sB[p][1][bB  + ((sl ^ bx)  * 8)];
            acc[0] = __builtin_amdgcn_mfma_f32_16x16x32_bf16(ah0, bh, acc[0], 0, 0, 0);
            acc[0] = __builtin_amdgcn_mfma_f32_16x16x32_bf16(ah0, bl, acc[0], 0, 0, 0);
            acc[0] = __builtin_amdgcn_mfma_f32_16x16x32_bf16(al0, bh, acc[0], 0, 0, 0);
            acc[1] = __builtin_amdgcn_mfma_f32_16x16x32_bf16(ah1, bh, acc[1], 0, 0, 0);
            acc[1] = __builtin_amdgcn_mfma_f32_16x16x32_bf16(ah1, bl, acc[1], 0, 0, 0);
            acc[1] = __builtin_amdgcn_mfma_f32_16x16x32_bf16(al1, bh, acc[1], 0, 0, 0);
        }
        if (c < 7) G3_WRITE((c + 1) & 1);    // other buffer: no WAR with current
                                             // readers; visible after next barrier
    }
#undef G3_LOAD
#undef G3_WRITE

    // epilogue: C/D col=fr, row=fs*4+q within each 16x16 frag
    #pragma unroll
    for (int i = 0; i < 2; ++i)
        #pragma unroll
        for (int q = 0; q < 4; ++q)
            ws_mx[(size_t)(rt * 32 + i * 16 + fs * 4 + q) * HID_ + ct * 64 + wv * 16 + fr]
                = acc[i][q];
}

// ---------------------------------------------------------------------------
// Stage 1b: per-row mobius epilogue, ONE WAVE PER ROW (no barriers).
// ---------------------------------------------------------------------------
__global__ __launch_bounds__(256) void mobius_rows_kernel(
    const float* __restrict__ query,
    const float* __restrict__ bq, const float* __restrict__ bk,
    const float* __restrict__ bv,
    float* __restrict__ ws_qkv, float* __restrict__ ws_gamma)
{
    const int lane = threadIdx.x & 63;
    const int wv   = threadIdx.x >> 6;
    const int row  = blockIdx.x * 4 + wv;     // 0..1535
    const int which = row >> 9;
    const int rr    = row & 511;              // b*S + s
    const float* __restrict__ bias = (which == 0) ? bq : (which == 1) ? bk : bv;
    float* mrow = ws_qkv + (size_t)row * HID_;
    const float* xrow = query + (size_t)((rr & 255) * 2 + (rr >> 8)) * HID_;

    float m[8], x[8], bb[8];
    *(float4*)&m[0]  = ((const float4*)mrow)[lane * 2];
    *(float4*)&m[4]  = ((const float4*)mrow)[lane * 2 + 1];
    *(float4*)&x[0]  = ((const float4*)xrow)[lane * 2];
    *(float4*)&x[4]  = ((const float4*)xrow)[lane * 2 + 1];
    *(float4*)&bb[0] = ((const float4*)bias)[lane * 2];
    *(float4*)&bb[4] = ((const float4*)bias)[lane * 2 + 1];

    float x2p = 0.f, m2p = 0.f, b2p = 0.f;
    #pragma unroll
    for (int j = 0; j < 8; ++j) {
        x2p = fmaf(x[j], x[j], x2p);
        m2p = fmaf(m[j], m[j], m2p);
        b2p = fmaf(bb[j], bb[j], b2p);
    }
    const float x2s = wsum64(x2p);
    const float mn2 = wsum64(m2p);
    const float b2s = wsum64(b2p);
    const float xn = fmaxf(sqrtf(x2s), 1e-15f);
    const float mn = fmaxf(sqrtf(mn2), 1e-15f);
    // mobius_matvec: res = tanh(mn/xn * artanh(xn)) * mx/mn
    const float fac = tanhf(mn / xn * artanh_c(xn)) / mn;
    float r[8];
    float r2p = 0.f, ryp = 0.f;
    #pragma unroll
    for (int j = 0; j < 8; ++j) {
        r[j] = fac * m[j];
        r2p = fmaf(r[j], r[j], r2p);
        ryp = fmaf(r[j], bb[j], ryp);
    }
    const float r2s = wsum64(r2p);
    const float ry  = wsum64(ryp);
    // mobius_add(r, bias)
    const float a_c = 1.f + 2.f * ry + b2s;
    const float b_c = 1.f - r2s;
    const float den = 1.f + 2.f * ry + r2s * b2s;
    const float inv_den = 1.f / fmaxf(den, 1e-15f);
    float h[8];
    float h2p = 0.f;
    #pragma unroll
    for (int j = 0; j < 8; ++j) {
        h[j] = (a_c * r[j] + b_c * bb[j]) * inv_den;
        h2p = fmaf(h[j], h[j], h2p);
    }
    const float h2s = wsum64(h2p);
    float hn = fmaxf(sqrtf(h2s), 1e-15f);
    float pf = 1.f;
    if (hn > 0.996f) { pf = 0.996f / hn; hn = 0.996f; }   // projx
    const float lf = artanh_c(hn) / hn * pf;               // logmap0 (512-dim)
    float l[8];
    float l2p = 0.f;
    #pragma unroll
    for (int j = 0; j < 8; ++j) {
        l[j] = lf * h[j];
        l2p = fmaf(l[j], l[j], l2p);
    }
    // expmap0 over flat 64-chunks: chunk j = lanes j*8 .. j*8+7
    float cs = l2p;
    cs += __shfl_xor(cs, 1, 64);
    cs += __shfl_xor(cs, 2, 64);
    cs += __shfl_xor(cs, 4, 64);
    const float cn = fmaxf(sqrtf(cs), 1e-15f);
    const float th = tanhf(cn);
    const float sc = th / cn;
    float o[8];
    #pragma unroll
    for (int j = 0; j < 8; ++j) o[j] = sc * l[j];
    ((float4*)mrow)[lane * 2]     = *(float4*)&o[0];
    ((float4*)mrow)[lane * 2 + 1] = *(float4*)&o[4];
    if (which == 2 && (lane & 7) == 0) {
        const int j = lane >> 3;
        // gamma = 2 / max(1 - ||vl_chunk||^2, eps); ||vl_chunk|| = tanh(cn)
        ws_gamma[(size_t)rr * NH_ + j] = 2.f / fmaxf(1.f - th * th, 1e-15f);
    }
}

// ---------------------------------------------------------------------------
// Stage 2+3 FUSED, v5 = v2 skeleton (512 blocks x 512 threads, q-tile 8,
// two 128-row K halves, d-split lane pairs) + 4-term grouped-rcp inner loop.
// ---------------------------------------------------------------------------
__global__ __launch_bounds__(512, 4) void attn_kernel(
    const float* __restrict__ ws_qkv, const float* __restrict__ gamma,
    float* __restrict__ probs, float* __restrict__ lc)
{
    const int tid = threadIdx.x;
    const int bh  = blockIdx.x >> 5;
    const int q0  = (blockIdx.x & 31) * 8;
    const float* __restrict__ ql = ws_qkv + (size_t)bh * (S_ * HD_);
    const float* __restrict__ kl = ws_qkv + (size_t)BSH + (size_t)bh * (S_ * HD_);
    const float* __restrict__ vl = ws_qkv + (size_t)2 * BSH + (size_t)bh * (S_ * HD_);

    __shared__ __align__(16) float kS[128 * 64];   // 32 KB, swizzled
    __shared__ __align__(16) float qS[8 * 64];     // 2 KB
    __shared__ __align__(16) float pS[8 * 256];    // 8 KB: p*gamma, [q_local][n]
    __shared__ float gS[S_];                       // 1 KB
    __shared__ float k2S[128];                     // per-row |k|^2, per half
    __shared__ float nomP[8][8][64];               // 16 KB phase-B partials
    __shared__ float dnS[8];

    // gamma in flat-chunk order == [b][h][n] flat => contiguous at bh*S_
    if (tid < 256) gS[tid] = gamma[(size_t)bh * S_ + tid];
    if (tid < 128) ((float4*)qS)[tid] = ((const float4*)(ql + (size_t)q0 * 64))[tid];
    __syncthreads();

    const int lane = tid & 63;
    const int q_l  = tid >> 6;        // 0..7 == wave id == q index
    const int n_i  = lane & 31;
    const int dh   = lane >> 5;       // d-half: 0 or 1
    const int d0   = dh * 32;

    float qv[32];
    #pragma unroll
    for (int c = 0; c < 8; ++c)
        *(float4*)&qv[c * 4] = *(const float4*)&qS[q_l * 64 + d0 + c * 4];
    float q2p = 0.f;
    #pragma unroll
    for (int d = 0; d < 32; ++d) q2p = fmaf(qv[d], qv[d], q2p);
    const float q2 = q2p + __shfl_xor(q2p, 32, 64);
    const float b_c = 1.f - q2;
    float* __restrict__ prow = probs + ((size_t)(bh * S_ + q0 + q_l)) * S_;

    const int c4 = tid & 15;        // staging: 16B slice
    const int nb = tid >> 4;        // staging: row 0..31
    float sp = 0.f, spg = 0.f;

    for (int half = 0; half < 2; ++half) {
        __syncthreads();            // protect kS/k2S reuse across halves
        #pragma unroll
        for (int jj = 0; jj < 4; ++jj) {
            const int n = nb + 32 * jj;   // 0..127
            const float4 v = *(const float4*)(kl + ((size_t)(half * 128 + n)) * 64 + c4 * 4);
            *(float4*)&kS[n * 64 + ((c4 ^ (n & 15)) * 4)] = v;
            // per-row |k|^2: reduce 16 chunk-partials over the 16 lanes sharing nb
            float pk = fmaf(v.x, v.x, fmaf(v.y, v.y, fmaf(v.z, v.z, v.w * v.w)));
            pk += __shfl_xor(pk, 1, 64);
            pk += __shfl_xor(pk, 2, 64);
            pk += __shfl_xor(pk, 4, 64);
            pk += __shfl_xor(pk, 8, 64);
            if (c4 == 0) k2S[n] = pk;
        }
        __syncthreads();
        #pragma unroll
        for (int j = 0; j < 4; ++j) {
            const int n = n_i + 32 * j;   // within half
            float kv[32];
            #pragma unroll
            for (int c = 0; c < 8; ++c) {
                const int sl = dh * 8 + c;          // this lane's 16B slices
                *(float4*)&kv[c * 4] = *(const float4*)&kS[n * 64 + ((sl ^ (n & 15)) * 4)];
            }
            float s0 = 0.f, s1 = 0.f;
            #pragma unroll
            for (int d = 0; d < 32; d += 2) {
                s0 = fmaf(qv[d],     kv[d],     s0);
                s1 = fmaf(qv[d + 1], kv[d + 1], s1);
            }
            float s = s0 + s1;
            s += __shfl_xor(s, 32, 64);              // merge d-halves
            const float k2  = k2S[n];
            const float a_c = 1.f - 2.f * s + k2;
            const float den = fmaxf(fmaf(q2, k2, 1.f - 2.f * s), 1e-15f);
            const float ra  = __builtin_amdgcn_rcpf(a_c);
            const float r_c = b_c * ra;
            const float scale = den * den * ra * ra;   // den^2 / a_c^2
            const float c2  = 1e-30f * scale;
            // GROUPED RCP (4-term): 8 rcp per lane instead of 32
            float isA = 0.f, isB = 0.f;
            #pragma unroll
            for (int g = 0; g < 8; g += 2) {
                {
                    const int bse = g * 4;
                    const float w0 = fmaf(r_c, kv[bse + 0], -qv[bse + 0]);
                    const float w1 = fmaf(r_c, kv[bse + 1], -qv[bse + 1]);
                    const float w2 = fmaf(r_c, kv[bse + 2], -qv[bse + 2]);
                    const float w3 = fmaf(r_c, kv[bse + 3], -qv[bse + 3]);
                    const float ga = fmaf(w0, w0, c2), gb = fmaf(w1, w1, c2);
                    const float gc = fmaf(w2, w2, c2), gd = fmaf(w3, w3, c2);
                    const float pab = ga * gb, pcd = gc * gd;
                    const float num = fmaf(ga + gb, pcd, (gc + gd) * pab);
                    isA = fmaf(num, __builtin_amdgcn_rcpf(pab * pcd), isA);
                }
                {
                    const int bse = (g + 1) * 4;
                    const float w0 = fmaf(r_c, kv[bse + 0], -qv[bse + 0]);
                    const float w1 = fmaf(r_c, kv[bse + 1], -qv[bse + 1]);
                    const float w2 = fmaf(r_c, kv[bse + 2], -qv[bse + 2]);
                    const float w3 = fmaf(r_c, kv[bse + 3], -qv[bse + 3]);
                    const float ga = fmaf(w0, w0, c2), gb = fmaf(w1, w1, c2);
                    const float gc = fmaf(w2, w2, c2), gd = fmaf(w3, w3, c2);
                    const float pab = ga * gb, pcd = gc * gd;
                    const float num = fmaf(ga + gb, pcd, (gc + gd) * pab);
                    isB = fmaf(num, __builtin_amdgcn_rcpf(pab * pcd), isB);
                }
            }
            float invsum = isA + isB;
            invsum += __shfl_xor(invsum, 32, 64);    // merge d-halves
            const float t1 = __builtin_amdgcn_rsqf(scale * invsum);
            const float p = 0.5f - 0.5f * fminf(t1, 0.9999999f);
            const int gn = half * 128 + n;
            if (dh == 0) {
                prow[gn] = p;
                const float g = gS[gn];
                pS[q_l * 256 + gn] = p * g;
                sp += p; spg += p * g;
            }
        }
    }
    // denom: dh==1 lanes hold 0, so a plain wave-sum counts each pair once
    sp  = wsum64(sp);
    spg = wsum64(spg);
    if (lane == 0) dnS[q_l] = spg - sp;   // denom = sum p*(g-1)
    __syncthreads();

    // Phase B: wave w owns n in [32w, 32w+32), all 8 q; lane = d
    const int w = q_l, d = lane;
    float acc[8] = {};
    const float* __restrict__ vbase = vl + (size_t)(w * 32) * 64;
    #pragma unroll
    for (int i4 = 0; i4 < 8; ++i4) {
        float vv[4];
        #pragma unroll
        for (int j2 = 0; j2 < 4; ++j2) vv[j2] = vbase[(size_t)(i4 * 4 + j2) * 64 + d];
        #pragma unroll
        for (int qq = 0; qq < 8; ++qq) {
            const float4 pq = *(const float4*)&pS[qq * 256 + w * 32 + i4 * 4]; // broadcast
            acc[qq] = fmaf(pq.x, vv[0], acc[qq]);
            acc[qq] = fmaf(pq.y, vv[1], acc[qq]);
            acc[qq] = fmaf(pq.z, vv[2], acc[qq]);
            acc[qq] = fmaf(pq.w, vv[3], acc[qq]);
        }
    }
    #pragma unroll
    for (int qq = 0; qq < 8; ++qq) nomP[w][qq][d] = acc[qq];
    __syncthreads();

    // final: thread owns (q = q_l, d = lane); whole wave shares one q
    {
        const int qq = q_l;
        float nom = 0.f;
        #pragma unroll
        for (int w2 = 0; w2 < 8; ++w2) nom += nomP[w2][qq][d];
        const float dd = dnS[qq];
        const float adn = fmaxf(fabsf(dd), 1e-10f);
        const float sden = (dd >= 0.f) ? adn : -adn;
        const float m = nom / sden;
        const float ss = wsum64(m * m);
        const float nn = fmaxf(sqrtf(ss), 1e-15f);
        const float s1 = tanhf(0.5f * artanh_c(nn));     // mobius_scalar_mul(0.5)
        const float res = s1 * m / nn;
        const float nres = fmaxf(s1, 1e-15f);            // ||res|| = s1 >= 0
        lc[((size_t)(bh * S_ + q0 + qq)) * HD_ + d] = (artanh_c(nres) / nres) * res;
    }
}

// ---------------------------------------------------------------------------
// Stage 4: gather heads -> [B,Q,512] row, expmap0 over 512, store [S,B,HID].
// ---------------------------------------------------------------------------
__global__ __launch_bounds__(256) void outproj_kernel(
    const float* __restrict__ lc, float* __restrict__ out0)
{
    const int t = threadIdx.x;
    const int s = blockIdx.x & (S_ - 1);
    const int b = blockIdx.x >> 8;
    __shared__ float red[256];
    const int h0 = t >> 6, d0 = t & 63;
    const int e1 = t + 256;
    const int h1 = e1 >> 6, d1 = e1 & 63;
    const float v0 = lc[(((size_t)(b * NH_ + h0)) * S_ + s) * HD_ + d0];
    const float v1 = lc[(((size_t)(b * NH_ + h1)) * S_ + s) * HD_ + d1];
    const float ss = block_sum_256(v0 * v0 + v1 * v1, red);
    const float nn = fmaxf(sqrtf(ss), 1e-15f);
    const float f = tanhf(nn) / nn;
    float* orow = out0 + ((size_t)(s * B_ + b)) * HID_;
    orow[t] = f * v0;
    orow[t + 256] = f * v1;
}

extern "C" void kernel_launch(void* const* d_in, const int* in_sizes, int n_in,
                              void* d_out, int out_size, void* d_ws, size_t ws_size,
                              hipStream_t stream) {
    (void)in_sizes; (void)n_in; (void)out_size; (void)ws_size;
    const float* query = (const float*)d_in[0];
    const float* Wq = (const float*)d_in[1];
    const float* bq = (const float*)d_in[2];
    const float* Wk = (const float*)d_in[3];
    const float* bk = (const float*)d_in[4];
    const float* Wv = (const float*)d_in[5];
    const float* bv = (const float*)d_in[6];

    float* out0  = (float*)d_out;                          // [S,B,HID] = 262144
    float* probs = out0 + (size_t)S_ * B_ * HID_;          // [B,NH,S,S] = 1048576

    float* ws       = (float*)d_ws;
    float* ws_qkv   = ws;                                  // mx -> ql|kl|vl : 3*262144 floats
    float* ws_gamma = ws + (size_t)3 * BSH;                // 4096 floats, flat chunk order
    float* ws_lc    = ws + (size_t)3 * BSH + 4096;         // 131072 floats (NO alias: attn
                                                           // writes lc while other blocks read ql)

    gemm3_fused_kernel<<<dim3(384), dim3(256), 0, stream>>>(query, Wq, Wk, Wv, ws_qkv);
    mobius_rows_kernel<<<dim3(384), dim3(256), 0, stream>>>(query, bq, bk, bv, ws_qkv, ws_gamma);
    attn_kernel<<<dim3(512), dim3(512), 0, stream>>>(ws_qkv, ws_gamma, probs, ws_lc);
    outproj_kernel<<<dim3(B_ * S_), dim3(256), 0, stream>>>(ws_lc, out0);
}